// Round 1
// 304.319 us; speedup vs baseline: 1.0947x; 1.0947x over previous
//
#include <hip/hip_runtime.h>

#define Bn 8
#define Cn 3
#define Sn 1024
#define DIMn 768
#define Hn 3
#define HDn 256
#define BCHn 72
#define SnHD (Sn*HDn)

typedef __bf16 bf16x8 __attribute__((ext_vector_type(8)));
typedef float f32x4 __attribute__((ext_vector_type(4)));
typedef float f32x16 __attribute__((ext_vector_type(16)));
typedef unsigned short u16x8 __attribute__((ext_vector_type(8)));
typedef unsigned short u16x4 __attribute__((ext_vector_type(4)));
typedef unsigned u32x2 __attribute__((ext_vector_type(2)));
typedef unsigned u32x4 __attribute__((ext_vector_type(4)));

static __device__ __forceinline__ unsigned short f2bf(float f){
  unsigned u = __builtin_bit_cast(unsigned, f);
  u += 0x7fffu + ((u >> 16) & 1u);
  return (unsigned short)(u >> 16);
}
static __device__ __forceinline__ unsigned pk2(float a, float b){
  return (unsigned)f2bf(a) | ((unsigned)f2bf(b) << 16);
}
static __device__ __forceinline__ u16x4 cvt4(float4 v){
  u16x4 r = { f2bf(v.x), f2bf(v.y), f2bf(v.z), f2bf(v.w) };
  return r;
}
static __device__ __forceinline__ bf16x8 ld8(const void* p){
  return __builtin_bit_cast(bf16x8, *(const u16x8*)p);
}
static __device__ __forceinline__ float fexp2(float x){
#if __has_builtin(__builtin_amdgcn_exp2f)
  return __builtin_amdgcn_exp2f(x);
#else
  return exp2f(x);
#endif
}

#if __has_builtin(__builtin_amdgcn_global_load_lds)
#define HAVE_ASYNC 1
static __device__ __forceinline__ void async16(const void* g, void* l){
  __builtin_amdgcn_global_load_lds((const __attribute__((address_space(1))) void*)g,
                                   (__attribute__((address_space(3))) void*)l, 16, 0, 0);
}
#else
#define HAVE_ASYNC 0
#endif

// From 8 C-regs of a 32x32 MFMA (rows (r&3)+8*(r>>2)+4*hi, col=lane&31), build the
// bf16x8 operand whose lane holds k=(lane>>5)*8+j for the 16-k chunk those rows form.
// w0/w1 = lower 8 k, w2/w3 = upper 8 k; lo/hi half exchange == permlane32_swap.
static __device__ __forceinline__ bf16x8 pack8(const float* t, int hi){
  unsigned A0 = pk2(t[0], t[1]), A1 = pk2(t[2], t[3]);
  unsigned B0 = pk2(t[4], t[5]), B1 = pk2(t[6], t[7]);
#if __has_builtin(__builtin_amdgcn_permlane32_swap)
  u32x2 r0 = __builtin_amdgcn_permlane32_swap(A0, B0, false, false);
  u32x2 r1 = __builtin_amdgcn_permlane32_swap(A1, B1, false, false);
  u32x4 w = { r0[0], r1[0], r0[1], r1[1] };
#else
  unsigned sA0 = (unsigned)__shfl_xor((int)A0, 32), sA1 = (unsigned)__shfl_xor((int)A1, 32);
  unsigned sB0 = (unsigned)__shfl_xor((int)B0, 32), sB1 = (unsigned)__shfl_xor((int)B1, 32);
  u32x4 w = { hi ? sB0 : A0, hi ? sB1 : A1, hi ? B0 : sA0, hi ? B1 : sA1 };
#endif
  (void)hi;
  return __builtin_bit_cast(bf16x8, w);
}

// ---------------- Kernel 0: W -> bf16 ----------------
// Wq (pre-scaled by log2e/16) is stored in MFMA-A-fragment order:
// [h][ks=4][etile*4+kstep=32][lane=64][8 bf16]  (1 KB per fragment)
// Wk/Wv stay row-linear for projkv.
__global__ __launch_bounds__(256) void wprep(
    const float* __restrict__ Wq, const float* __restrict__ Wk, const float* __restrict__ Wv,
    unsigned short* __restrict__ Wb)
{
  const int which = blockIdx.z, h = blockIdx.y;
  const float* src = which == 0 ? Wq : (which == 1 ? Wk : Wv);
  const float scale = (which == 0) ? 0.09016844136545405f : 1.0f; // log2(e)/16
  const int off = blockIdx.x*1024 + threadIdx.x*4;
  float4 v = *(const float4*)(src + (long)h*65536 + off);
  v.x *= scale; v.y *= scale; v.z *= scale; v.w *= scale;
  long o;
  if (which == 0){
    const int e = off >> 8, k0 = off & 255;
    const int ks = k0 >> 6, kst = (k0 >> 4) & 3, hb = (k0 >> 3) & 1, j0 = k0 & 7;
    o = (long)h*65536 + ks*16384 + ((e>>5)*4 + kst)*512 + (((hb<<5)|(e&31))*8) + j0;
  } else {
    o = (long)(which*Hn + h)*65536 + off;
  }
  *(u16x4*)(Wb + o) = cvt4(v);
}

// ---------------- Kernel 1: fused K and V^T projections ----------------
// Same compute as before; epilogues now store K and V^T in MFMA-fragment order:
// Kw: [bch][ttile=32][kc=16][lane=64][8]   (A-frag: row t=lane&31, k=kc*16+(lane>>5)*8+j)
// Vt: [bch][ttile=32][etile*2+ts=16][lane=64][8] (A-frag: row e=etile*32+(lane&31), k=t)
__global__ __launch_bounds__(256, 2) void projkv(
    const float* __restrict__ x, const unsigned short* __restrict__ Wb,
    const float* __restrict__ bk, const float* __restrict__ bv,
    unsigned short* __restrict__ Kw, unsigned short* __restrict__ Vt)
{
  __shared__ alignas(16) unsigned short SM[23040]; // 46,080 B
  unsigned short* XA  = SM;          // [64][40]
  unsigned short* WkL = SM + 2560;   // [256][40]
  unsigned short* WvL = SM + 12800;  // [256][40]
  unsigned short* TK  = SM;          // epilogue [64][264]
  unsigned short* TV  = SM;          // epilogue [256][72]

  const int tid = threadIdx.x, lane = tid & 63, wave = tid >> 6;
  const int l15 = lane & 15, quad = lane >> 4;
  const int bch = blockIdx.y;
  const int h = bch % Hn, c = (bch / Hn) % Cn, b = bch / (Hn*Cn);
  const int tb = blockIdx.x * 64;
  const long xb_ = ((long)(b*Cn + c)*Sn + tb)*DIMn + h*HDn;
  const unsigned short* Wkb = Wb + (long)(1*Hn + h)*65536;
  const unsigned short* Wvb = Wb + (long)(2*Hn + h)*65536;

  float4 xr[2]; u16x8 wk[4], wv[4];
  auto loadg = [&](int ks){
    const int k0 = ks*32;
    #pragma unroll
    for (int i = 0; i < 2; ++i){
      int id = tid + i*256;
      xr[i] = *(const float4*)(x + xb_ + (long)(id>>3)*DIMn + k0 + (id&7)*4);
    }
    #pragma unroll
    for (int i = 0; i < 4; ++i){
      int id = tid + i*256;
      wk[i] = *(const u16x8*)(Wkb + (id>>2)*HDn + k0 + (id&3)*8);
      wv[i] = *(const u16x8*)(Wvb + (id>>2)*HDn + k0 + (id&3)*8);
    }
  };
  loadg(0);

  f32x4 Ka[16] = {}; f32x4 Va[4][4] = {};
  for (int ks = 0; ks < 8; ++ks){
    #pragma unroll
    for (int i = 0; i < 2; ++i){
      int id = tid + i*256;
      *(u16x4*)&XA[(id>>3)*40 + (id&7)*4] = cvt4(xr[i]);
    }
    #pragma unroll
    for (int i = 0; i < 4; ++i){
      int id = tid + i*256;
      *(u16x8*)&WkL[(id>>2)*40 + (id&3)*8] = wk[i];
      *(u16x8*)&WvL[(id>>2)*40 + (id&3)*8] = wv[i];
    }
    __syncthreads();
    if (ks < 7) loadg(ks + 1);
    bf16x8 af = ld8(&XA[(wave*16 + l15)*40 + quad*8]);
    #pragma unroll
    for (int nt = 0; nt < 16; ++nt){
      bf16x8 bw = ld8(&WkL[(nt*16 + l15)*40 + quad*8]);
      Ka[nt] = __builtin_amdgcn_mfma_f32_16x16x32_bf16(af, bw, Ka[nt], 0, 0, 0);
    }
    bf16x8 avf[4], bxf[4];
    #pragma unroll
    for (int j = 0; j < 4; ++j) avf[j] = ld8(&WvL[((wave*4 + j)*16 + l15)*40 + quad*8]);
    #pragma unroll
    for (int n = 0; n < 4; ++n) bxf[n] = ld8(&XA[(n*16 + l15)*40 + quad*8]);
    #pragma unroll
    for (int j = 0; j < 4; ++j)
      #pragma unroll
      for (int n = 0; n < 4; ++n)
        Va[j][n] = __builtin_amdgcn_mfma_f32_16x16x32_bf16(avf[j], bxf[n], Va[j][n], 0, 0, 0);
    __syncthreads();
  }

  const float* bkh = bk + h*HDn;
  const float* bvh = bv + h*HDn;
  // K epilogue
  #pragma unroll
  for (int nt = 0; nt < 16; ++nt){
    const float bb = bkh[nt*16 + l15];
    #pragma unroll
    for (int r = 0; r < 4; ++r)
      TK[(wave*16 + quad*4 + r)*264 + nt*16 + l15] = f2bf(Ka[nt][r] + bb);
  }
  __syncthreads();
  {
    unsigned short* Kg = Kw + (long)bch*SnHD + (long)(tb>>5)*8192;
    #pragma unroll
    for (int i = 0; i < 8; ++i){
      const int f = wave*8 + i;
      const int tl = f >> 4, kc = f & 15;
      *(u16x8*)(Kg + (long)tl*8192 + kc*512 + lane*8) =
        *(const u16x8*)&TK[(tl*32 + (lane&31))*264 + kc*16 + (lane>>5)*8];
    }
  }
  __syncthreads();
  // Vt epilogue
  #pragma unroll
  for (int j = 0; j < 4; ++j){
    #pragma unroll
    for (int n = 0; n < 4; ++n){
      #pragma unroll
      for (int r = 0; r < 4; ++r){
        const int er = wave*64 + j*16 + quad*4 + r;
        TV[er*72 + n*16 + l15] = f2bf(Va[j][n][r] + bvh[er]);
      }
    }
  }
  __syncthreads();
  {
    unsigned short* Vg = Vt + (long)bch*SnHD + (long)(tb>>5)*8192;
    #pragma unroll
    for (int i = 0; i < 8; ++i){
      const int f = wave*8 + i;
      const int tcl = f >> 4, r2 = f & 15;
      *(u16x8*)(Vg + (long)tcl*8192 + r2*512 + lane*8) =
        *(const u16x8*)&TV[((r2>>1)*32 + (lane&31))*72 + tcl*32 + (r2&1)*16 + (lane>>5)*8];
    }
  }
}

// ---------------- Kernel 2: fused Q projection + attention (32x32 MFMA) ----------------
// 128 q-rows per block, 4 waves x 32 q. Swapped QK (S^T = K.Q), in-register softmax via
// permlane32_swap, O^T = V^T.P^T, row-sum l in registers. K/V^T double-buffered in LDS
// in fragment-linear order (stride-1 ds_read_b128 with immediate offsets).
__global__ __launch_bounds__(256, 2) void attn(
    const float* __restrict__ x, const unsigned short* __restrict__ Wb,
    const float* __restrict__ bq,
    const unsigned short* __restrict__ Kw, const unsigned short* __restrict__ Vt,
    float* __restrict__ out)
{
  // LDS map (bytes):
  //  phase A : XL @0 [128 q][64 k] bf16 (16B-XOR swizzled), WL @16384 (32 x 1KB Wq frags)
  //  phase B : KL0 @0, KL1 @16384 ; VL0 @32768, VL1 @49152 (16 x 1KB frags each)
  //  bias    : bql @65536 (256 f32)
  //  epilogue: TB @ wave*16384 [32 q][128 e] f32 (16B-XOR swizzled)
  __shared__ alignas(16) char SM[66560];

  const int tid = threadIdx.x, lane = tid & 63, wave = tid >> 6;
  const int l31 = lane & 31, hi = lane >> 5;
  const int bid = blockIdx.x;
  const int g = bid >> 3;
  const int bch = (g & ~7) | (bid & 7);      // 8 q-tiles of one bch share an XCD
  const int qt = g & 7;
  const int h = bch % Hn, c = (bch / Hn) % Cn, b = bch / (Hn*Cn);
  const int q0 = qt * 128;
  const long xb_ = ((long)(b*Cn + c)*Sn + q0)*DIMn + h*HDn;

  float* bql = (float*)(SM + 65536);
  bql[tid] = bq[h*HDn + tid] * 0.09016844136545405f;

  // ---- Phase A: Q' = X.Wq^T via mfma(Wq, X^T) -> C[e][q], then pack to B-frags ----
  float4 xv[4][2];
  auto loadX = [&](int ks){
    #pragma unroll
    for (int i = 0; i < 4; ++i){
      const int vid = tid + i*256;
      const int q = vid >> 3, kg = vid & 7;
      const float* p = x + xb_ + (long)q*DIMn + ks*64 + kg*8;
      xv[i][0] = *(const float4*)p;
      xv[i][1] = *(const float4*)(p + 4);
    }
  };
  const unsigned short* Wq2 = Wb + (long)h*65536;
  auto issueW = [&](int ks){
    #pragma unroll
    for (int i = 0; i < 8; ++i){
      const int f = wave*8 + i;
#if HAVE_ASYNC
      async16(Wq2 + (long)ks*16384 + f*512 + lane*8, SM + 16384 + f*1024);
#else
      *(u16x8*)(SM + 16384 + f*1024 + lane*16) =
          *(const u16x8*)(Wq2 + (long)ks*16384 + f*512 + lane*8);
#endif
    }
  };
  loadX(0);
  f32x16 acc[8] = {};
  for (int ks = 0; ks < 4; ++ks){
    #pragma unroll
    for (int i = 0; i < 4; ++i){
      const int vid = tid + i*256;
      const int q = vid >> 3, kg = vid & 7;
      u16x4 lo = cvt4(xv[i][0]), hh = cvt4(xv[i][1]);
      u16x8 w = { lo[0], lo[1], lo[2], lo[3], hh[0], hh[1], hh[2], hh[3] };
      *(u16x8*)(SM + q*128 + ((kg*16) ^ ((q & 7) << 4))) = w;
    }
    issueW(ks);
    __syncthreads();
    if (ks < 3) loadX(ks + 1);
    #pragma unroll
    for (int kst = 0; kst < 4; ++kst){
      bf16x8 xb = ld8(SM + (wave*32 + l31)*128 + ((kst*32 + hi*16) ^ ((l31 & 7) << 4)));
      #pragma unroll
      for (int et = 0; et < 8; ++et){
        bf16x8 af = ld8(SM + 16384 + (et*4 + kst)*1024 + lane*16);
        acc[et] = __builtin_amdgcn_mfma_f32_32x32x16_bf16(af, xb, acc[et], 0, 0, 0);
      }
    }
    __syncthreads();
  }

  // ---- stage chunk 0; fold scaled bias; pack Q into B-fragments ----
  const unsigned short* Kb = Kw + (long)bch*SnHD;
  const unsigned short* Vb = Vt + (long)bch*SnHD;
  auto stageKV = [&](int jt, int buf){
    const long kb2 = (long)jt * 8192;
    #pragma unroll
    for (int i = 0; i < 4; ++i){
      const int f = wave*4 + i;
#if HAVE_ASYNC
      async16(Kb + kb2 + f*512 + lane*8, SM + buf*16384 + f*1024);
#else
      *(u16x8*)(SM + buf*16384 + f*1024 + lane*16) = *(const u16x8*)(Kb + kb2 + f*512 + lane*8);
#endif
    }
    #pragma unroll
    for (int i = 0; i < 4; ++i){
      const int f = wave*4 + i;
#if HAVE_ASYNC
      async16(Vb + kb2 + f*512 + lane*8, SM + 32768 + buf*16384 + f*1024);
#else
      *(u16x8*)(SM + 32768 + buf*16384 + f*1024 + lane*16) = *(const u16x8*)(Vb + kb2 + f*512 + lane*8);
#endif
    }
  };
  stageKV(0, 0);

  bf16x8 qf[16];
  #pragma unroll
  for (int et = 0; et < 8; ++et){
    float t[16];
    #pragma unroll
    for (int G = 0; G < 4; ++G){
      f32x4 bb = *(const f32x4*)&bql[et*32 + 8*G + 4*hi];
      t[4*G+0] = acc[et][4*G+0] + bb[0];
      t[4*G+1] = acc[et][4*G+1] + bb[1];
      t[4*G+2] = acc[et][4*G+2] + bb[2];
      t[4*G+3] = acc[et][4*G+3] + bb[3];
    }
    qf[2*et]   = pack8(t,     hi);
    qf[2*et+1] = pack8(t + 8, hi);
  }
  __syncthreads();

  // ---- Phase B: 32 chunks of 32 keys ----
  f32x16 o[8] = {};
  float lsum = 0.f;
  #pragma unroll 2
  for (int jt = 0; jt < 32; ++jt){
    const int buf = jt & 1;
    if (jt < 31) stageKV(jt + 1, buf ^ 1);
    // S^T = K.Q  (rows = keys, cols = q)
    f32x16 s = {};
    const char* KLb = SM + buf*16384 + lane*16;
    #pragma unroll
    for (int kc = 0; kc < 16; ++kc){
      bf16x8 kf = ld8(KLb + kc*1024);
      s = __builtin_amdgcn_mfma_f32_32x32x16_bf16(kf, qf[kc], s, 0, 0, 0);
    }
    float p[16];
    #pragma unroll
    for (int i = 0; i < 16; ++i) p[i] = fexp2(s[i]);
    lsum += (((p[0]+p[1])+(p[2]+p[3])) + ((p[4]+p[5])+(p[6]+p[7])))
          + (((p[8]+p[9])+(p[10]+p[11])) + ((p[12]+p[13])+(p[14]+p[15])));
    bf16x8 pB0 = pack8(p, hi), pB1 = pack8(p + 8, hi);
    // O^T += V^T.P^T
    const char* VLb = SM + 32768 + buf*16384 + lane*16;
    #pragma unroll
    for (int et = 0; et < 8; ++et){
      bf16x8 v0 = ld8(VLb + (et*2+0)*1024);
      o[et] = __builtin_amdgcn_mfma_f32_32x32x16_bf16(v0, pB0, o[et], 0, 0, 0);
      bf16x8 v1 = ld8(VLb + (et*2+1)*1024);
      o[et] = __builtin_amdgcn_mfma_f32_32x32x16_bf16(v1, pB1, o[et], 0, 0, 0);
    }
    __syncthreads();
  }

  // ---- Epilogue: scale by 1/l, LDS-transpose O^T, coalesced f32 stores ----
  const float lt = lsum + __shfl_xor(lsum, 32);
  const float inv = 1.0f / lt;
  #pragma unroll
  for (int et = 0; et < 8; ++et)
    #pragma unroll
    for (int r = 0; r < 16; ++r) o[et][r] *= inv;

  char* TB = SM + wave*16384;
  #pragma unroll
  for (int pass = 0; pass < 2; ++pass){
    #pragma unroll
    for (int e2 = 0; e2 < 4; ++e2){
      const int et = pass*4 + e2;
      #pragma unroll
      for (int G = 0; G < 4; ++G){
        f32x4 w = { o[et][4*G+0], o[et][4*G+1], o[et][4*G+2], o[et][4*G+3] };
        const int el0 = e2*32 + 8*G + 4*hi;
        *(f32x4*)(TB + l31*512 + ((el0*4) ^ ((l31 & 7) << 4))) = w;
      }
    }
    #pragma unroll
    for (int i = 0; i < 16; ++i){
      const int qr = i*2 + hi;
      f32x4 v = *(const f32x4*)(TB + qr*512 + ((l31*16) ^ ((qr & 7) << 4)));
      float* op = out + ((long)(b*Sn + q0 + wave*32 + qr)*Cn + c)*DIMn + h*HDn + pass*128 + l31*4;
      *(f32x4*)op = v;
    }
  }
}

extern "C" void kernel_launch(void* const* d_in, const int* in_sizes, int n_in,
                              void* d_out, int out_size, void* d_ws, size_t ws_size,
                              hipStream_t stream) {
  const float* x  = (const float*)d_in[0];
  const float* Wq = (const float*)d_in[1];
  const float* bq = (const float*)d_in[2];
  const float* Wk = (const float*)d_in[3];
  const float* bk = (const float*)d_in[4];
  const float* Wv = (const float*)d_in[5];
  const float* bv = (const float*)d_in[6];
  float* out = (float*)d_out;
  unsigned short* Kw = (unsigned short*)d_ws;              // [72][32][16][64][8] bf16 frags
  unsigned short* Vt = Kw + (size_t)BCHn * SnHD;           // [72][32][16][64][8] bf16 frags
  unsigned short* Wb = Vt + (size_t)BCHn * SnHD;           // Wq frags + Wk/Wv linear

  wprep<<<dim3(64, Hn, 3), 256, 0, stream>>>(Wq, Wk, Wv, Wb);
  projkv<<<dim3(16, BCHn), 256, 0, stream>>>(x, Wb, bk, bv, Kw, Vt);
  attn<<<dim3(BCHn * 8), 256, 0, stream>>>(x, Wb, bq, Kw, Vt, out);
}